// Round 1
// 564.136 us; speedup vs baseline: 1.1408x; 1.1408x over previous
//
#include <hip/hip_runtime.h>
#include <hip/hip_bf16.h>

// MOELoraLinear: out = x@W_base^T + b_base + SCALING * router-weighted LoRA.
// LoRA-up folded into main GEMM via K-extension: Xext[8192,4224]=[bf16(x)|hw'|0pad],
// Wext[4096,4224]=[bf16(W_base)|lora_B|0pad]; one bf16 MFMA GEMM K=4224 + bias.
// R3: k_main rebuilt as 256x256 8-phase counted-vmcnt template (m201 structure):
//   8 waves, BK=64, 128KiB dbuf LDS, (row&7)<<4 XOR swizzle (linear gload_lds dest +
//   inverse-swizzled global src + swizzled ds_read), vmcnt(4) at phases 4/8 only,
//   setprio around MFMA clusters, bijective XCD block swizzle. K padded 4160->4224.

typedef unsigned short u16;
typedef __attribute__((ext_vector_type(8))) short short8;       // 8 bf16 (MFMA A/B frag)
typedef __attribute__((ext_vector_type(8))) unsigned short u16x8;
typedef __attribute__((ext_vector_type(4))) float f32x4;        // MFMA C/D frag

#define AS1(p) ((const __attribute__((address_space(1))) void*)(p))
#define AS3(p) ((__attribute__((address_space(3))) void*)(p))

constexpr int KM   = 4224;   // extended+padded K (66 * 64), row stride of Xext/Wext
constexpr int NOUT = 4096;

__device__ __forceinline__ u16 f2bf(float f) {
    union { float f; unsigned int u; } v; v.f = f;
    unsigned int r = v.u + 0x7fffu + ((v.u >> 16) & 1u);   // RNE
    return (u16)(r >> 16);
}

// ---- fused: x fp32 -> bf16 into Xext[:, :4096]  +  per-block column sums ----
// grid 512: b = blk>>7, sc = blk&127 -> rows [b*2048 + sc*16, +16)
__global__ __launch_bounds__(256) void k_convx(const float* __restrict__ x,
                                               u16* __restrict__ Xext,
                                               float* __restrict__ colpart) {
    const int t = threadIdx.x;
    const int row0 = (blockIdx.x >> 7) * 2048 + (blockIdx.x & 127) * 16;
    float4 cs[4] = {{0,0,0,0},{0,0,0,0},{0,0,0,0},{0,0,0,0}};   // [g*2+h]
    for (int r = 0; r < 16; ++r) {
        size_t roff = (size_t)(row0 + r) * 4096;
        #pragma unroll
        for (int g = 0; g < 2; ++g) {
            int col = g * 2048 + t * 8;
            const float4* p = (const float4*)(x + roff + col);
            float4 v0 = p[0], v1 = p[1];
            cs[2*g].x += v0.x; cs[2*g].y += v0.y; cs[2*g].z += v0.z; cs[2*g].w += v0.w;
            cs[2*g+1].x += v1.x; cs[2*g+1].y += v1.y; cs[2*g+1].z += v1.z; cs[2*g+1].w += v1.w;
            u16x8 o;
            o[0]=f2bf(v0.x); o[1]=f2bf(v0.y); o[2]=f2bf(v0.z); o[3]=f2bf(v0.w);
            o[4]=f2bf(v1.x); o[5]=f2bf(v1.y); o[6]=f2bf(v1.z); o[7]=f2bf(v1.w);
            *(u16x8*)(Xext + (size_t)(row0 + r) * KM + col) = o;
        }
    }
    float* cp = colpart + (size_t)blockIdx.x * 4096;
    #pragma unroll
    for (int g = 0; g < 2; ++g) {
        *(float4*)(cp + g * 2048 + t * 8)     = cs[2*g];
        *(float4*)(cp + g * 2048 + t * 8 + 4) = cs[2*g+1];
    }
}

// ---- logits_raw[b,e] = sum_col colsum[b,col] * rW[e,col]  (grid 32 = b*8+e) ----
__global__ __launch_bounds__(256) void k_logit(const float* __restrict__ colpart,
                                               const float* __restrict__ rW,
                                               float* __restrict__ logits) {
    const int b = blockIdx.x >> 3, e = blockIdx.x & 7;
    const int t = threadIdx.x;
    const int c0 = t * 16;
    float4 rw[4];
    #pragma unroll
    for (int j = 0; j < 4; ++j) rw[j] = *(const float4*)(rW + e * 4096 + c0 + j * 4);
    float acc = 0.f;
    for (int sc = 0; sc < 128; ++sc) {
        const float4* p = (const float4*)(colpart + ((size_t)(b * 128 + sc)) * 4096 + c0);
        #pragma unroll
        for (int j = 0; j < 4; ++j) {
            float4 v = p[j];
            acc += v.x * rw[j].x + v.y * rw[j].y + v.z * rw[j].z + v.w * rw[j].w;
        }
    }
    __shared__ float red[256];
    red[t] = acc;
    __syncthreads();
    for (int off = 128; off > 0; off >>= 1) {
        if (t < off) red[t] += red[t + off];
        __syncthreads();
    }
    if (t == 0) logits[b * 8 + e] = red[0];
}

// ---- W_base fp32 [4096][4096] -> bf16 into Wext[:, :4096] ----
__global__ void k_conv8(const float* __restrict__ src, u16* __restrict__ dst) {
    size_t t = (size_t)blockIdx.x * 256 + threadIdx.x;
    size_t base = t * 8;
    size_t row = base >> 12;
    int col = (int)(base & 4095);
    const float4* s = (const float4*)(src + base);
    float4 v0 = s[0], v1 = s[1];
    u16x8 o;
    o[0]=f2bf(v0.x); o[1]=f2bf(v0.y); o[2]=f2bf(v0.z); o[3]=f2bf(v0.w);
    o[4]=f2bf(v1.x); o[5]=f2bf(v1.y); o[6]=f2bf(v1.z); o[7]=f2bf(v1.w);
    *(u16x8*)(dst + row * KM + col) = o;
}

// ---- lora_B [E,O,R] fp32 -> Wext[o][4096 + e*8 + r]; also zero K-pad [4160,4224) ----
__global__ void k_wlora(const float* __restrict__ lb, u16* __restrict__ Wext) {
    int f = blockIdx.x * 256 + threadIdx.x;
    int e = f >> 15, o = (f >> 3) & 4095, r = f & 7;
    Wext[(size_t)o * KM + 4096 + e * 8 + r] = f2bf(lb[f]);
    // pad zero: f in [0, 262144) == 4096 rows x 64 pad cols
    Wext[(size_t)(f >> 6) * KM + 4160 + (f & 63)] = 0;
}

// ---- lora_A [E,R,D] fp32 -> Abf [64][4096] bf16 ----
__global__ void k_abf(const float* __restrict__ la, u16* __restrict__ Abf) {
    int f = blockIdx.x * 256 + threadIdx.x;
    Abf[f] = f2bf(la[f]);
}

// ---- h-GEMM: Xext[:, 4096+er] = f2bf( (Xbf @ Abf^T)[m,er] * SCALING*softmax(...)[b(m),e] )
// grid 256 blocks x 256 thr (4 waves). M-tile 32. Each wave owns K-chunk of 1024,
// private double-buffered LDS, no in-loop barriers; cross-wave LDS reduce at end.
// Also zero-fills the K-pad columns [4160,4224) of its 32 rows.
__global__ __launch_bounds__(256) void k_hgemm(const u16* __restrict__ Xb,
                                               const u16* __restrict__ Ab,
                                               const float* __restrict__ logits,
                                               const float* __restrict__ rb,
                                               u16* __restrict__ Hout) {
    __shared__ u16 As[8 * 1024];     // [wave*2+buf][32*32]
    __shared__ u16 Bs[8 * 2048];     // [wave*2+buf][64*32]
    __shared__ float Red[4 * 2048];  // [wave][32*64]
    __shared__ float wscL[8];
    const int tid = threadIdx.x, lane = tid & 63, w = tid >> 6;
    const int m0 = blockIdx.x * 32;
    const int b = blockIdx.x >> 6;      // batch (2048 rows = 64 blocks per batch)

    if (tid < 8) {
        float l[8], mx = -1e30f;
        #pragma unroll
        for (int j = 0; j < 8; ++j) {
            l[j] = logits[b * 8 + j] * (1.0f / 2048.0f) + rb[j];
            mx = fmaxf(mx, l[j]);
        }
        float s = 0.f;
        #pragma unroll
        for (int j = 0; j < 8; ++j) s += expf(l[j] - mx);
        wscL[tid] = 2.0f * expf(l[tid] - mx) / s;   // SCALING = 2.0
    }
    // drain the logits/rb loads so they don't pollute vmcnt bookkeeping below
    asm volatile("s_waitcnt vmcnt(0)" ::: "memory");

    f32x4 acc[2][4] = {};
    const int kbase = w * 1024;

    auto issue = [&](int it, int buf) {
        const int kt = kbase + it * 32;
        u16* Aw = As + (w * 2 + buf) * 1024;
        u16* Bw = Bs + (w * 2 + buf) * 2048;
        #pragma unroll
        for (int i = 0; i < 2; ++i) {
            int f = lane + i * 64;
            __builtin_amdgcn_global_load_lds(
                AS1(Xb + (size_t)(m0 + (f >> 2)) * KM + kt + (f & 3) * 8),
                AS3(Aw + f * 8), 16, 0, 0);
        }
        #pragma unroll
        for (int i = 0; i < 4; ++i) {
            int f = lane + i * 64;
            __builtin_amdgcn_global_load_lds(
                AS1(Ab + (size_t)(f >> 2) * 4096 + kt + (f & 3) * 8),
                AS3(Bw + f * 8), 16, 0, 0);
        }
    };

    issue(0, 0);
    for (int it = 0; it < 32; ++it) {
        const int buf = it & 1;
        if (it + 1 < 32) {
            issue(it + 1, buf ^ 1);
            asm volatile("s_waitcnt vmcnt(6)" ::: "memory");   // drain the 6 older (this iter's) DMAs
        } else {
            asm volatile("s_waitcnt vmcnt(0)" ::: "memory");
        }
        const u16* Aw = As + (w * 2 + buf) * 1024;
        const u16* Bw = Bs + (w * 2 + buf) * 2048;
        short8 af[2], bfr[4];
        #pragma unroll
        for (int mi = 0; mi < 2; ++mi)
            af[mi] = *(const short8*)(Aw + (mi * 16 + (lane & 15)) * 32 + (lane >> 4) * 8);
        #pragma unroll
        for (int nj = 0; nj < 4; ++nj)
            bfr[nj] = *(const short8*)(Bw + (nj * 16 + (lane & 15)) * 32 + (lane >> 4) * 8);
        #pragma unroll
        for (int mi = 0; mi < 2; ++mi)
            #pragma unroll
            for (int nj = 0; nj < 4; ++nj)
                acc[mi][nj] = __builtin_amdgcn_mfma_f32_16x16x32_bf16(af[mi], bfr[nj], acc[mi][nj], 0, 0, 0);
        asm volatile("" ::: "memory");
    }

    const int quad = lane >> 4, lcol = lane & 15;
    #pragma unroll
    for (int mi = 0; mi < 2; ++mi)
        #pragma unroll
        for (int nj = 0; nj < 4; ++nj)
            #pragma unroll
            for (int r = 0; r < 4; ++r)
                Red[w * 2048 + (mi * 16 + quad * 4 + r) * 64 + nj * 16 + lcol] = acc[mi][nj][r];
    __syncthreads();

    const int o = tid * 8, row = o >> 6, col = o & 63;
    float s0=0,s1=0,s2=0,s3=0,s4=0,s5=0,s6=0,s7=0;
    #pragma unroll
    for (int ww = 0; ww < 4; ++ww) {
        const float4* p = (const float4*)(Red + ww * 2048 + o);
        float4 v0 = p[0], v1 = p[1];
        s0+=v0.x; s1+=v0.y; s2+=v0.z; s3+=v0.w;
        s4+=v1.x; s5+=v1.y; s6+=v1.z; s7+=v1.w;
    }
    const float wgt = wscL[col >> 3];
    u16x8 out;
    out[0]=f2bf(s0*wgt); out[1]=f2bf(s1*wgt); out[2]=f2bf(s2*wgt); out[3]=f2bf(s3*wgt);
    out[4]=f2bf(s4*wgt); out[5]=f2bf(s5*wgt); out[6]=f2bf(s6*wgt); out[7]=f2bf(s7*wgt);
    *(u16x8*)(Hout + (size_t)(m0 + row) * KM + 4096 + col) = out;
    // zero K-pad: 32 rows x 64 cols per block
    u16x8 zz = {0,0,0,0,0,0,0,0};
    *(u16x8*)(Hout + (size_t)(m0 + (tid >> 3)) * KM + 4160 + (tid & 7) * 8) = zz;
}

// ================= main GEMM: 256x256 tile, BK=64, 8-phase counted-vmcnt =================
// C[8192,4096] = Xext @ Wext^T + bias. K = 4224 = 66 tiles of 64, 2 tiles/iteration.
// LDS (bytes): buf b in {0,1}: A half h @ b*65536 + h*16384 ; B half h @ b*65536 + 32768 + h*16384.
// Swizzle: logical (row, colbyte) stored at colbyte ^ ((row&7)<<4) within each 128B row.
//   - gload_lds dest stays LINEAR; the global SOURCE col is pre-inverse-swizzled (rule 21).
//   - ds_read addr: XOR term depends only on lane -> folds into 2 per-lane base offsets.
// Staging schedule (iter computes tiles t=2i buf0, t+1 buf1), 1 half-tile/phase:
//   P1:A(t+1)h0  P2:A(t+1)h1  P3:B(t+2)h0  P4:B(t+2)h1 | vmcnt(4)
//   P5:A(t+2)h0  P6:A(t+2)h1  P7:B(t+3)h0  P8:B(t+3)h1 | vmcnt(4)
// Each region is re-staged >=1 full barrier after its last ds_read (B read wholly in P1/P5;
// A read through P4/P8). Last iteration (i=32): only P1/P2 stage; vmcnt(0) at P4.

#define LDB_(bufB) do { \
    const char* bp_ = ldsc + bBaseB + (bufB); \
    _Pragma("unroll") \
    for (int nj_ = 0; nj_ < 4; ++nj_) { \
        bf[nj_][0] = *(const short8*)(bp_ + nj_ * 2048 + rdk0); \
        bf[nj_][1] = *(const short8*)(bp_ + nj_ * 2048 + rdk1); \
    } \
} while (0)

#define LDA_(bufB, pq) do { \
    const char* ap_ = ldsc + aBaseB + (bufB) + (pq) * 4096; \
    af[0][0] = *(const short8*)(ap_ + rdk0); \
    af[0][1] = *(const short8*)(ap_ + rdk1); \
    af[1][0] = *(const short8*)(ap_ + 2048 + rdk0); \
    af[1][1] = *(const short8*)(ap_ + 2048 + rdk1); \
} while (0)

#define MFMA_(pq) do { \
    __builtin_amdgcn_s_barrier(); \
    asm volatile("s_waitcnt lgkmcnt(0)" ::: "memory"); \
    __builtin_amdgcn_sched_barrier(0); \
    __builtin_amdgcn_s_setprio(1); \
    _Pragma("unroll") \
    for (int q_ = 0; q_ < 2; ++q_) { \
        _Pragma("unroll") \
        for (int nj_ = 0; nj_ < 4; ++nj_) { \
            acc[(pq)*2+q_][nj_] = __builtin_amdgcn_mfma_f32_16x16x32_bf16(af[q_][0], bf[nj_][0], acc[(pq)*2+q_][nj_], 0, 0, 0); \
            acc[(pq)*2+q_][nj_] = __builtin_amdgcn_mfma_f32_16x16x32_bf16(af[q_][1], bf[nj_][1], acc[(pq)*2+q_][nj_], 0, 0, 0); \
        } \
    } \
    __builtin_amdgcn_s_setprio(0); \
    __builtin_amdgcn_sched_barrier(0); \
} while (0)

#define ENDPH_() __builtin_amdgcn_s_barrier()

__global__ __launch_bounds__(512, 2) void k_main(const u16* __restrict__ A, const u16* __restrict__ B,
                                                 const float* __restrict__ bias, float* __restrict__ C) {
    __shared__ __align__(16) u16 lds[65536];   // 128 KiB
    const char* ldsc = (const char*)lds;
    const int tid = threadIdx.x;
    const int lane = tid & 63;
    const int w = tid >> 6;
    const int wm = w >> 2;        // 0..1  (M half)
    const int wn = w & 3;         // 0..3  (N quarter)
    const int lr = lane & 15, hi = lane >> 4;

    // bijective XCD swizzle: 512 blocks, 64/XCD; tiles 32(M) x 16(N), N fast (A-panel L2 reuse)
    const int bid = blockIdx.x;
    const int swz = (bid & 7) * 64 + (bid >> 3);
    const int m0 = (swz >> 4) * 256;
    const int n0 = (swz & 15) * 256;

    // ds_read byte offsets within a half-tile region (swizzled; XOR depends only on lane)
    const int csw = (lr & 7) << 4;
    const int rdk0 = lr * 128 + ((hi * 16) ^ csw);        // kk=0
    const int rdk1 = lr * 128 + ((64 + hi * 16) ^ csw);   // kk=1
    const int aBaseB = wm * 16384;                                      // buf0 A
    const int bBaseB = 32768 + (wn >> 1) * 16384 + (wn & 1) * 8192;     // buf0 B

    // staging: thread tid writes linear LDS bytes [r*8192 + tid*16, +16); logical row
    // = r*64 + (tid>>3), source col pre-inverse-swizzled by ((row&7)<<4).
    const int srow = tid >> 3;                                   // 0..63
    const int scol = ((tid & 7) ^ ((tid >> 3) & 7)) * 8;         // elements, [0,64)
    const int so0 = srow * KM + scol;
    const int so1 = (64 + srow) * KM + scol;
    const u16* Am0 = A + (size_t)m0 * KM;
    const u16* Am1 = A + (size_t)(m0 + 128) * KM;
    const u16* Bm0 = B + (size_t)n0 * KM;
    const u16* Bm1 = B + (size_t)(n0 + 128) * KM;
    u16* ldst = lds + tid * 8;                                   // element base for DMA dest

    auto stage = [&](const u16* src, int t, int regionEl) {
        __builtin_amdgcn_global_load_lds(AS1(src + so0 + t * 64), AS3(ldst + regionEl), 16, 0, 0);
        __builtin_amdgcn_global_load_lds(AS1(src + so1 + t * 64), AS3(ldst + regionEl + 4096), 16, 0, 0);
    };

    f32x4 acc[8][4] = {};

    // prologue: B(0), A(0), B(1); wait for B(0)+A(0), leave B(1) in flight
    stage(Bm0, 0, 16384);
    stage(Bm1, 0, 24576);
    stage(Am0, 0, 0);
    stage(Am1, 0, 8192);
    stage(Bm0, 1, 32768 + 16384);
    stage(Bm1, 1, 32768 + 24576);
    asm volatile("s_waitcnt vmcnt(4)" ::: "memory");
    __builtin_amdgcn_s_barrier();

    #pragma unroll 1
    for (int i = 0; i < 33; ++i) {
        const int t = i * 2;
        const bool nl = (i < 32);
        short8 af[2][2];
        short8 bf[4][2];
        // -------- K-tile t (buf0) --------
        LDB_(0); LDA_(0, 0);
        stage(Am0, t + 1, 32768);
        MFMA_(0); ENDPH_();
        LDA_(0, 1);
        stage(Am1, t + 1, 32768 + 8192);
        MFMA_(1); ENDPH_();
        LDA_(0, 2);
        if (nl) stage(Bm0, t + 2, 16384);
        MFMA_(2); ENDPH_();
        LDA_(0, 3);
        if (nl) stage(Bm1, t + 2, 24576);
        MFMA_(3);
        if (nl) { asm volatile("s_waitcnt vmcnt(4)" ::: "memory"); }
        else    { asm volatile("s_waitcnt vmcnt(0)" ::: "memory"); }
        ENDPH_();
        // -------- K-tile t+1 (buf1) --------
        LDB_(65536); LDA_(65536, 0);
        if (nl) stage(Am0, t + 2, 0);
        MFMA_(0); ENDPH_();
        LDA_(65536, 1);
        if (nl) stage(Am1, t + 2, 8192);
        MFMA_(1); ENDPH_();
        LDA_(65536, 2);
        if (nl) stage(Bm0, t + 3, 32768 + 16384);
        MFMA_(2); ENDPH_();
        LDA_(65536, 3);
        if (nl) stage(Bm1, t + 3, 32768 + 24576);
        MFMA_(3);
        if (nl) { asm volatile("s_waitcnt vmcnt(4)" ::: "memory"); }
        ENDPH_();
    }

    // epilogue: C[row][col] = acc + bias, C/D layout col=lane&15, row=(lane>>4)*4+r
    const int colb = n0 + wn * 64 + lr;
    const int rowb = m0 + wm * 128 + hi * 4;
    #pragma unroll
    for (int nj = 0; nj < 4; ++nj) {
        const int col = colb + nj * 16;
        const float bv = bias[col];
        #pragma unroll
        for (int mi = 0; mi < 8; ++mi) {
            float* Cp = C + (size_t)(rowb + mi * 16) * NOUT + col;
            #pragma unroll
            for (int r = 0; r < 4; ++r)
                Cp[(size_t)r * NOUT] = acc[mi][nj][r] + bv;
        }
    }
}

extern "C" void kernel_launch(void* const* d_in, const int* in_sizes, int n_in,
                              void* d_out, int out_size, void* d_ws, size_t ws_size,
                              hipStream_t stream) {
    const float* x  = (const float*)d_in[0];   // [4,2048,4096]
    const float* Wb = (const float*)d_in[1];   // [4096,4096]
    const float* bb = (const float*)d_in[2];   // [4096]
    const float* lA = (const float*)d_in[3];   // [8,8,4096]
    const float* lB = (const float*)d_in[4];   // [8,4096,8]
    const float* rW = (const float*)d_in[5];   // [8,4096]
    const float* rb = (const float*)d_in[6];   // [8]
    float* out = (float*)d_out;                // [4,2048,4096] fp32

    char* ws = (char*)d_ws;
    float* logits = (float*)ws;                            // 32 fp32
    u16* Abf      = (u16*)(ws + 256);                      // 64*4096 bf16 = 512 KiB
    u16* Xext     = (u16*)(ws + 524800);                   // 8192*4224 bf16 = 69.2 MB
    u16* Wext     = (u16*)(ws + 524800 + 69206016ULL);     // 4096*4224 bf16 = 34.6 MB
    // colpart [512][4096] fp32 = 8 MB, overlaid on Wext region: it is fully
    // consumed by k_logit BEFORE k_conv8/k_wlora write Wext (stream-ordered).
    float* colpart = (float*)Wext;

    k_abf   <<<1024, 256, 0, stream>>>(lA, Abf);             // lora_A -> bf16
    k_convx <<<512,  256, 0, stream>>>(x, Xext, colpart);    // x -> bf16 + column sums
    k_logit <<<32,   256, 0, stream>>>(colpart, rW, logits); // raw router logits
    k_hgemm <<<256,  256, 0, stream>>>(Xext, Abf, logits, rb, Xext); // hw' -> Xext[:,4096:4160] + pad0
    k_conv8 <<<8192, 256, 0, stream>>>(Wb, Wext);            // W_base -> Wext[:, :4096]
    k_wlora <<<1024, 256, 0, stream>>>(lB, Wext);            // lora_B -> Wext[:, 4096:4160] + pad0
    k_main  <<<512,  512, 0, stream>>>(Xext, Wext, bb, out); // 256^2 8-phase GEMM + bias
}

// Round 2
// 551.989 us; speedup vs baseline: 1.1659x; 1.0220x over previous
//
#include <hip/hip_runtime.h>
#include <hip/hip_bf16.h>

// MOELoraLinear: out = x@W_base^T + b_base + SCALING * router-weighted LoRA.
// LoRA-up folded into main GEMM via K-extension: Xext[8192,4224]=[bf16(x)|hw'|0pad],
// Wext[4096,4224]=[bf16(W_base)|lora_B|0pad]; one bf16 MFMA GEMM K=4224 + bias.
// R4: (a) k_main: quarter-granular A staging -> progressive-need legalizes deeper
//     counted vmcnt (8/6/8/6, min 3-phase slack vs R1's 2); MFMA k0-sweep/k1-sweep
//     removes dependent back-to-back pairs. LDS image identical to R1 (verified).
//     (b) k_logit (grid 32, serialized 64MB re-read) -> k_red (64 blk) + k_lgt (32 blk).

typedef unsigned short u16;
typedef __attribute__((ext_vector_type(8))) short short8;       // 8 bf16 (MFMA A/B frag)
typedef __attribute__((ext_vector_type(8))) unsigned short u16x8;
typedef __attribute__((ext_vector_type(4))) float f32x4;        // MFMA C/D frag

#define AS1(p) ((const __attribute__((address_space(1))) void*)(p))
#define AS3(p) ((__attribute__((address_space(3))) void*)(p))

constexpr int KM   = 4224;   // extended+padded K (66 * 64), row stride of Xext/Wext
constexpr int NOUT = 4096;

__device__ __forceinline__ u16 f2bf(float f) {
    union { float f; unsigned int u; } v; v.f = f;
    unsigned int r = v.u + 0x7fffu + ((v.u >> 16) & 1u);   // RNE
    return (u16)(r >> 16);
}

// ---- fused: x fp32 -> bf16 into Xext[:, :4096]  +  per-block column sums ----
// grid 512: b = blk>>7, sc = blk&127 -> rows [b*2048 + sc*16, +16)
__global__ __launch_bounds__(256) void k_convx(const float* __restrict__ x,
                                               u16* __restrict__ Xext,
                                               float* __restrict__ colpart) {
    const int t = threadIdx.x;
    const int row0 = (blockIdx.x >> 7) * 2048 + (blockIdx.x & 127) * 16;
    float4 cs[4] = {{0,0,0,0},{0,0,0,0},{0,0,0,0},{0,0,0,0}};   // [g*2+h]
    for (int r = 0; r < 16; ++r) {
        size_t roff = (size_t)(row0 + r) * 4096;
        #pragma unroll
        for (int g = 0; g < 2; ++g) {
            int col = g * 2048 + t * 8;
            const float4* p = (const float4*)(x + roff + col);
            float4 v0 = p[0], v1 = p[1];
            cs[2*g].x += v0.x; cs[2*g].y += v0.y; cs[2*g].z += v0.z; cs[2*g].w += v0.w;
            cs[2*g+1].x += v1.x; cs[2*g+1].y += v1.y; cs[2*g+1].z += v1.z; cs[2*g+1].w += v1.w;
            u16x8 o;
            o[0]=f2bf(v0.x); o[1]=f2bf(v0.y); o[2]=f2bf(v0.z); o[3]=f2bf(v0.w);
            o[4]=f2bf(v1.x); o[5]=f2bf(v1.y); o[6]=f2bf(v1.z); o[7]=f2bf(v1.w);
            *(u16x8*)(Xext + (size_t)(row0 + r) * KM + col) = o;
        }
    }
    float* cp = colpart + (size_t)blockIdx.x * 4096;
    #pragma unroll
    for (int g = 0; g < 2; ++g) {
        *(float4*)(cp + g * 2048 + t * 8)     = cs[2*g];
        *(float4*)(cp + g * 2048 + t * 8 + 4) = cs[2*g+1];
    }
}

// ---- colsum[b][c] = sum_sc colpart[b*128+sc][c]; grid 64 = b*16+chunk ----
__global__ __launch_bounds__(256) void k_red(const float* __restrict__ colpart,
                                             float* __restrict__ colsum) {
    const int b = blockIdx.x >> 4;
    const int col = (blockIdx.x & 15) * 256 + threadIdx.x;
    const float* p = colpart + (size_t)b * 128 * 4096 + col;
    float acc = 0.f;
    #pragma unroll 4
    for (int sc = 0; sc < 128; ++sc) acc += p[(size_t)sc * 4096];
    colsum[b * 4096 + col] = acc;
}

// ---- logits_raw[b,e] = sum_col colsum[b,col] * rW[e,col]  (grid 32 = b*8+e) ----
__global__ __launch_bounds__(256) void k_lgt(const float* __restrict__ colsum,
                                             const float* __restrict__ rW,
                                             float* __restrict__ logits) {
    const int b = blockIdx.x >> 3, e = blockIdx.x & 7;
    const int t = threadIdx.x;
    const float4* cp = (const float4*)(colsum + b * 4096 + t * 16);
    const float4* wp = (const float4*)(rW + e * 4096 + t * 16);
    float acc = 0.f;
    #pragma unroll
    for (int j = 0; j < 4; ++j) {
        float4 c = cp[j], w = wp[j];
        acc += c.x * w.x + c.y * w.y + c.z * w.z + c.w * w.w;
    }
    __shared__ float red[256];
    red[t] = acc;
    __syncthreads();
    for (int off = 128; off > 0; off >>= 1) {
        if (t < off) red[t] += red[t + off];
        __syncthreads();
    }
    if (t == 0) logits[b * 8 + e] = red[0];
}

// ---- W_base fp32 [4096][4096] -> bf16 into Wext[:, :4096] ----
__global__ void k_conv8(const float* __restrict__ src, u16* __restrict__ dst) {
    size_t t = (size_t)blockIdx.x * 256 + threadIdx.x;
    size_t base = t * 8;
    size_t row = base >> 12;
    int col = (int)(base & 4095);
    const float4* s = (const float4*)(src + base);
    float4 v0 = s[0], v1 = s[1];
    u16x8 o;
    o[0]=f2bf(v0.x); o[1]=f2bf(v0.y); o[2]=f2bf(v0.z); o[3]=f2bf(v0.w);
    o[4]=f2bf(v1.x); o[5]=f2bf(v1.y); o[6]=f2bf(v1.z); o[7]=f2bf(v1.w);
    *(u16x8*)(dst + row * KM + col) = o;
}

// ---- lora_B [E,O,R] fp32 -> Wext[o][4096 + e*8 + r]; also zero K-pad [4160,4224) ----
__global__ void k_wlora(const float* __restrict__ lb, u16* __restrict__ Wext) {
    int f = blockIdx.x * 256 + threadIdx.x;
    int e = f >> 15, o = (f >> 3) & 4095, r = f & 7;
    Wext[(size_t)o * KM + 4096 + e * 8 + r] = f2bf(lb[f]);
    // pad zero: f in [0, 262144) == 4096 rows x 64 pad cols
    Wext[(size_t)(f >> 6) * KM + 4160 + (f & 63)] = 0;
}

// ---- lora_A [E,R,D] fp32 -> Abf [64][4096] bf16 ----
__global__ void k_abf(const float* __restrict__ la, u16* __restrict__ Abf) {
    int f = blockIdx.x * 256 + threadIdx.x;
    Abf[f] = f2bf(la[f]);
}

// ---- h-GEMM: Xext[:, 4096+er] = f2bf( (Xbf @ Abf^T)[m,er] * SCALING*softmax(...)[b(m),e] )
// grid 256 blocks x 256 thr (4 waves). M-tile 32. Each wave owns K-chunk of 1024,
// private double-buffered LDS, no in-loop barriers; cross-wave LDS reduce at end.
// Also zero-fills the K-pad columns [4160,4224) of its 32 rows.
__global__ __launch_bounds__(256) void k_hgemm(const u16* __restrict__ Xb,
                                               const u16* __restrict__ Ab,
                                               const float* __restrict__ logits,
                                               const float* __restrict__ rb,
                                               u16* __restrict__ Hout) {
    __shared__ u16 As[8 * 1024];     // [wave*2+buf][32*32]
    __shared__ u16 Bs[8 * 2048];     // [wave*2+buf][64*32]
    __shared__ float Red[4 * 2048];  // [wave][32*64]
    __shared__ float wscL[8];
    const int tid = threadIdx.x, lane = tid & 63, w = tid >> 6;
    const int m0 = blockIdx.x * 32;
    const int b = blockIdx.x >> 6;      // batch (2048 rows = 64 blocks per batch)

    if (tid < 8) {
        float l[8], mx = -1e30f;
        #pragma unroll
        for (int j = 0; j < 8; ++j) {
            l[j] = logits[b * 8 + j] * (1.0f / 2048.0f) + rb[j];
            mx = fmaxf(mx, l[j]);
        }
        float s = 0.f;
        #pragma unroll
        for (int j = 0; j < 8; ++j) s += expf(l[j] - mx);
        wscL[tid] = 2.0f * expf(l[tid] - mx) / s;   // SCALING = 2.0
    }
    // drain the logits/rb loads so they don't pollute vmcnt bookkeeping below
    asm volatile("s_waitcnt vmcnt(0)" ::: "memory");

    f32x4 acc[2][4] = {};
    const int kbase = w * 1024;

    auto issue = [&](int it, int buf) {
        const int kt = kbase + it * 32;
        u16* Aw = As + (w * 2 + buf) * 1024;
        u16* Bw = Bs + (w * 2 + buf) * 2048;
        #pragma unroll
        for (int i = 0; i < 2; ++i) {
            int f = lane + i * 64;
            __builtin_amdgcn_global_load_lds(
                AS1(Xb + (size_t)(m0 + (f >> 2)) * KM + kt + (f & 3) * 8),
                AS3(Aw + f * 8), 16, 0, 0);
        }
        #pragma unroll
        for (int i = 0; i < 4; ++i) {
            int f = lane + i * 64;
            __builtin_amdgcn_global_load_lds(
                AS1(Ab + (size_t)(f >> 2) * 4096 + kt + (f & 3) * 8),
                AS3(Bw + f * 8), 16, 0, 0);
        }
    };

    issue(0, 0);
    for (int it = 0; it < 32; ++it) {
        const int buf = it & 1;
        if (it + 1 < 32) {
            issue(it + 1, buf ^ 1);
            asm volatile("s_waitcnt vmcnt(6)" ::: "memory");   // drain the 6 older (this iter's) DMAs
        } else {
            asm volatile("s_waitcnt vmcnt(0)" ::: "memory");
        }
        const u16* Aw = As + (w * 2 + buf) * 1024;
        const u16* Bw = Bs + (w * 2 + buf) * 2048;
        short8 af[2], bfr[4];
        #pragma unroll
        for (int mi = 0; mi < 2; ++mi)
            af[mi] = *(const short8*)(Aw + (mi * 16 + (lane & 15)) * 32 + (lane >> 4) * 8);
        #pragma unroll
        for (int nj = 0; nj < 4; ++nj)
            bfr[nj] = *(const short8*)(Bw + (nj * 16 + (lane & 15)) * 32 + (lane >> 4) * 8);
        #pragma unroll
        for (int mi = 0; mi < 2; ++mi)
            #pragma unroll
            for (int nj = 0; nj < 4; ++nj)
                acc[mi][nj] = __builtin_amdgcn_mfma_f32_16x16x32_bf16(af[mi], bfr[nj], acc[mi][nj], 0, 0, 0);
        asm volatile("" ::: "memory");
    }

    const int quad = lane >> 4, lcol = lane & 15;
    #pragma unroll
    for (int mi = 0; mi < 2; ++mi)
        #pragma unroll
        for (int nj = 0; nj < 4; ++nj)
            #pragma unroll
            for (int r = 0; r < 4; ++r)
                Red[w * 2048 + (mi * 16 + quad * 4 + r) * 64 + nj * 16 + lcol] = acc[mi][nj][r];
    __syncthreads();

    const int o = tid * 8, row = o >> 6, col = o & 63;
    float s0=0,s1=0,s2=0,s3=0,s4=0,s5=0,s6=0,s7=0;
    #pragma unroll
    for (int ww = 0; ww < 4; ++ww) {
        const float4* p = (const float4*)(Red + ww * 2048 + o);
        float4 v0 = p[0], v1 = p[1];
        s0+=v0.x; s1+=v0.y; s2+=v0.z; s3+=v0.w;
        s4+=v1.x; s5+=v1.y; s6+=v1.z; s7+=v1.w;
    }
    const float wgt = wscL[col >> 3];
    u16x8 out;
    out[0]=f2bf(s0*wgt); out[1]=f2bf(s1*wgt); out[2]=f2bf(s2*wgt); out[3]=f2bf(s3*wgt);
    out[4]=f2bf(s4*wgt); out[5]=f2bf(s5*wgt); out[6]=f2bf(s6*wgt); out[7]=f2bf(s7*wgt);
    *(u16x8*)(Hout + (size_t)(m0 + row) * KM + 4096 + col) = out;
    // zero K-pad: 32 rows x 64 cols per block
    u16x8 zz = {0,0,0,0,0,0,0,0};
    *(u16x8*)(Hout + (size_t)(m0 + (tid >> 3)) * KM + 4160 + (tid & 7) * 8) = zz;
}

// ================= main GEMM: 256x256 tile, BK=64, 8-phase counted-vmcnt =================
// C[8192,4096] = Xext @ Wext^T + bias. K = 4224 = 66 tiles of 64, 2 tiles/iteration.
// LDS (bytes): buf b in {0,1}: A @ b*65536 (q0:0-8K q1:8-16K q2:16-24K q3:24-32K);
//              B @ b*65536+32768 (h0: +0-16K, h1: +16-32K).
// Swizzle: logical (row, colbyte) stored at colbyte ^ ((row&7)<<4) within each 128B row.
// Staging (iter computes tiles t buf0, t+1 buf1), 2 loads per thread per phase:
//   P1:A(t+1){q0,q2}  P2:A(t+1){q1,q3}  P3:B(t+2)h0  P4:B(t+2)h1
//   P5:A(t+2){q0,q2}  P6:A(t+2){q1,q3}  P7:B(t+3)h0  P8:B(t+3)h1
// Progressive needs (block-wide): {q0,q2}+B-full before phase 1 of a tile; {q1,q3}
// before phase 3. Waits: end-P2 vmcnt(8), end-P4 vmcnt(6), end-P6 vmcnt(8),
// end-P8 vmcnt(6) -> every staged region has >=3 phases issue->wait slack.
// Tail (i=32): stages only P1/P2; waits become 8 / 2 / 0 / skip.

#define LDB_(bufB) do { \
    const char* bp_ = ldsc + bBaseB + (bufB); \
    _Pragma("unroll") \
    for (int nj_ = 0; nj_ < 4; ++nj_) { \
        bf[nj_][0] = *(const short8*)(bp_ + nj_ * 2048 + rdk0); \
        bf[nj_][1] = *(const short8*)(bp_ + nj_ * 2048 + rdk1); \
    } \
} while (0)

#define LDA_(bufB, pq) do { \
    const char* ap_ = ldsc + aBaseB + (bufB) + (pq) * 4096; \
    af[0][0] = *(const short8*)(ap_ + rdk0); \
    af[0][1] = *(const short8*)(ap_ + rdk1); \
    af[1][0] = *(const short8*)(ap_ + 2048 + rdk0); \
    af[1][1] = *(const short8*)(ap_ + 2048 + rdk1); \
} while (0)

// k0 sweep then k1 sweep: 8 independent MFMAs between dependent pairs
#define MFMA_(pq) do { \
    __builtin_amdgcn_s_barrier(); \
    asm volatile("s_waitcnt lgkmcnt(0)" ::: "memory"); \
    __builtin_amdgcn_sched_barrier(0); \
    __builtin_amdgcn_s_setprio(1); \
    _Pragma("unroll") \
    for (int k_ = 0; k_ < 2; ++k_) \
        _Pragma("unroll") \
        for (int q_ = 0; q_ < 2; ++q_) \
            _Pragma("unroll") \
            for (int nj_ = 0; nj_ < 4; ++nj_) \
                acc[(pq)*2+q_][nj_] = __builtin_amdgcn_mfma_f32_16x16x32_bf16(af[q_][k_], bf[nj_][k_], acc[(pq)*2+q_][nj_], 0, 0, 0); \
    __builtin_amdgcn_s_setprio(0); \
    __builtin_amdgcn_sched_barrier(0); \
} while (0)

#define ENDPH_() __builtin_amdgcn_s_barrier()
#define VM_(n)   asm volatile("s_waitcnt vmcnt(" #n ")" ::: "memory")

__global__ __launch_bounds__(512, 2) void k_main(const u16* __restrict__ A, const u16* __restrict__ B,
                                                 const float* __restrict__ bias, float* __restrict__ C) {
    __shared__ __align__(16) u16 lds[65536];   // 128 KiB
    const char* ldsc = (const char*)lds;
    const int tid = threadIdx.x;
    const int lane = tid & 63;
    const int w = tid >> 6;
    const int wm = w >> 2;        // 0..1  (M half)
    const int wn = w & 3;         // 0..3  (N quarter)
    const int lr = lane & 15, hi = lane >> 4;

    // bijective XCD swizzle: 512 blocks, 64/XCD; tiles 32(M) x 16(N), N fast (A-panel L2 reuse)
    const int bid = blockIdx.x;
    const int swz = (bid & 7) * 64 + (bid >> 3);
    const int m0 = (swz >> 4) * 256;
    const int n0 = (swz & 15) * 256;

    // ds_read byte offsets within a half-tile region (swizzled; XOR depends only on lane)
    const int csw = (lr & 7) << 4;
    const int rdk0 = lr * 128 + ((hi * 16) ^ csw);        // kk=0
    const int rdk1 = lr * 128 + ((64 + hi * 16) ^ csw);   // kk=1
    const int aBaseB = wm * 16384;                                      // buf0 A (wm half)
    const int bBaseB = 32768 + (wn >> 1) * 16384 + (wn & 1) * 8192;     // buf0 B

    // staging: thread tid writes linear LDS bytes [tid*16 + region]; logical row
    // = region_row0 + (tid>>3), source col pre-inverse-swizzled by ((row&7)<<4).
    const int srow = tid >> 3;                                   // 0..63
    const int scol = ((tid & 7) ^ ((tid >> 3) & 7)) * 8;         // elements, [0,64)
    const int so0 = srow * KM + scol;
    const int so1 = (64 + srow) * KM + scol;
    const u16* Am0 = A + (size_t)m0 * KM;
    const u16* Am1 = A + (size_t)(m0 + 128) * KM;
    const u16* Bm0 = B + (size_t)n0 * KM;
    const u16* Bm1 = B + (size_t)(n0 + 128) * KM;
    u16* ldst = lds + tid * 8;                                   // element base for DMA dest

    // B half-tile stage (rows r0..r0+127): 2 loads
    auto stageB = [&](const u16* src, int t, int regionEl) {
        __builtin_amdgcn_global_load_lds(AS1(src + so0 + t * 64), AS3(ldst + regionEl), 16, 0, 0);
        __builtin_amdgcn_global_load_lds(AS1(src + so1 + t * 64), AS3(ldst + regionEl + 4096), 16, 0, 0);
    };
    // A quarter-pair stage: which=0 -> {q0: rows 0-63, q2: rows 128-191};
    //                       which=1 -> {q1: rows 64-127, q3: rows 192-255}. 2 loads.
    auto stageA = [&](int t, int bufEl, int which) {
        const size_t ro = (size_t)(which * 64) * KM;
        __builtin_amdgcn_global_load_lds(AS1(Am0 + ro + so0 + t * 64),
                                         AS3(ldst + bufEl + which * 4096), 16, 0, 0);
        __builtin_amdgcn_global_load_lds(AS1(Am1 + ro + so0 + t * 64),
                                         AS3(ldst + bufEl + 8192 + which * 4096), 16, 0, 0);
    };

    f32x4 acc[8][4] = {};

    // prologue: B(0)h0, B(0)h1, A(0)w0, A(0)w1, B(1)h0, B(1)h1  (12 loads)
    stageB(Bm0, 0, 16384);
    stageB(Bm1, 0, 24576);
    stageA(0, 0, 0);
    stageA(0, 0, 1);
    stageB(Bm0, 1, 32768 + 16384);
    stageB(Bm1, 1, 32768 + 24576);
    VM_(6);                      // B(0) full + A(0){q0,q2} complete
    __builtin_amdgcn_s_barrier();

    #pragma unroll 1
    for (int i = 0; i < 33; ++i) {
        const int t = i * 2;
        const bool nl = (i < 32);
        short8 af[2][2];
        short8 bf[4][2];
        // -------- K-tile t (buf0) --------
        LDB_(0); LDA_(0, 0);
        stageA(t + 1, 32768, 0);
        MFMA_(0); ENDPH_();
        LDA_(0, 1);
        stageA(t + 1, 32768, 1);
        MFMA_(1); VM_(8); ENDPH_();                  // A(t){q1,q3} complete
        LDA_(0, 2);
        if (nl) stageB(Bm0, t + 2, 16384);
        MFMA_(2); ENDPH_();
        LDA_(0, 3);
        if (nl) stageB(Bm1, t + 2, 24576);
        MFMA_(3);
        if (nl) { VM_(6); } else { VM_(2); }         // B(t+1) + A(t+1){q0,q2}
        ENDPH_();
        // -------- K-tile t+1 (buf1) --------
        LDB_(65536); LDA_(65536, 0);
        if (nl) stageA(t + 2, 0, 0);
        MFMA_(0); ENDPH_();
        LDA_(65536, 1);
        if (nl) stageA(t + 2, 0, 1);
        MFMA_(1);
        if (nl) { VM_(8); } else { VM_(0); }         // A(t+1){q1,q3}
        ENDPH_();
        LDA_(65536, 2);
        if (nl) stageB(Bm0, t + 3, 32768 + 16384);
        MFMA_(2); ENDPH_();
        LDA_(65536, 3);
        if (nl) stageB(Bm1, t + 3, 32768 + 24576);
        MFMA_(3);
        if (nl) { VM_(6); }                          // B(t+2) + A(t+2){q0,q2}
        ENDPH_();
    }

    // epilogue: C[row][col] = acc + bias, C/D layout col=lane&15, row=(lane>>4)*4+r
    const int colb = n0 + wn * 64 + lr;
    const int rowb = m0 + wm * 128 + hi * 4;
    #pragma unroll
    for (int nj = 0; nj < 4; ++nj) {
        const int col = colb + nj * 16;
        const float bv = bias[col];
        #pragma unroll
        for (int mi = 0; mi < 8; ++mi) {
            float* Cp = C + (size_t)(rowb + mi * 16) * NOUT + col;
            #pragma unroll
            for (int r = 0; r < 4; ++r)
                Cp[(size_t)r * NOUT] = acc[mi][nj][r] + bv;
        }
    }
}

extern "C" void kernel_launch(void* const* d_in, const int* in_sizes, int n_in,
                              void* d_out, int out_size, void* d_ws, size_t ws_size,
                              hipStream_t stream) {
    const float* x  = (const float*)d_in[0];   // [4,2048,4096]
    const float* Wb = (const float*)d_in[1];   // [4096,4096]
    const float* bb = (const float*)d_in[2];   // [4096]
    const float* lA = (const float*)d_in[3];   // [8,8,4096]
    const float* lB = (const float*)d_in[4];   // [8,4096,8]
    const float* rW = (const float*)d_in[5];   // [8,4096]
    const float* rb = (const float*)d_in[6];   // [8]
    float* out = (float*)d_out;                // [4,2048,4096] fp32

    char* ws = (char*)d_ws;
    float* logits = (float*)ws;                            // 32 fp32
    u16* Abf      = (u16*)(ws + 256);                      // 64*4096 bf16 = 512 KiB
    u16* Xext     = (u16*)(ws + 524800);                   // 8192*4224 bf16 = 69.2 MB
    u16* Wext     = (u16*)(ws + 524800 + 69206016ULL);     // 4096*4224 bf16 = 34.6 MB
    // colpart [512][4096] fp32 = 8 MB, overlaid on Wext[0..8MB); colsum [4][4096] fp32
    // = 64 KiB overlaid at Wext+16MB. Both fully consumed (k_red/k_lgt) BEFORE
    // k_conv8/k_wlora write Wext (stream-ordered).
    float* colpart = (float*)Wext;
    float* colsum  = (float*)((char*)Wext + (16u << 20));

    k_abf   <<<1024, 256, 0, stream>>>(lA, Abf);             // lora_A -> bf16
    k_convx <<<512,  256, 0, stream>>>(x, Xext, colpart);    // x -> bf16 + column sums
    k_red   <<<64,   256, 0, stream>>>(colpart, colsum);     // colpart -> per-batch colsum
    k_lgt   <<<32,   256, 0, stream>>>(colsum, rW, logits);  // raw router logits
    k_hgemm <<<256,  256, 0, stream>>>(Xext, Abf, logits, rb, Xext); // hw' -> Xext[:,4096:4160] + pad0
    k_conv8 <<<8192, 256, 0, stream>>>(Wb, Wext);            // W_base -> Wext[:, :4096]
    k_wlora <<<1024, 256, 0, stream>>>(lB, Wext);            // lora_B -> Wext[:, 4096:4160] + pad0
    k_main  <<<512,  512, 0, stream>>>(Xext, Wext, bb, out); // 256^2 8-phase GEMM + bias
}